// Round 2
// baseline (511.900 us; speedup 1.0000x reference)
//
#include <hip/hip_runtime.h>
#include <hip/hip_bf16.h>

typedef __attribute__((ext_vector_type(4))) float  f32x4;
typedef __attribute__((ext_vector_type(8))) __bf16 bf16x8;

#define NB 2
#define NN 100000
#define NE 400000

__device__ __forceinline__ float tanh_f(float x) {
  float xc = fminf(fmaxf(x, -10.f), 10.f);
  float e = __expf(2.f * xc);
  return 1.f - 2.f / (e + 1.f);
}

// dtype-branched float load: bf=1 -> buffer is bf16, bf=0 -> fp32
__device__ __forceinline__ float ldf(const void* p, long i, int bf) {
  return bf ? (float)((const __bf16*)p)[i] : ((const float*)p)[i];
}

// flags[0]=mask-is-bytes, flags[1]=inputs-are-bf16, flags[2]=mfma-layout-ok
__global__ __launch_bounds__(256) void k_detect(const unsigned int* __restrict__ mw,
                                                const unsigned int* __restrict__ nodew,
                                                int* __restrict__ flags) {
  __shared__ int bad, good;
  const int t = threadIdx.x;
  if (t == 0) { bad = 0; good = 0; }
  __syncthreads();
  int my = 0;
  for (int i = t; i < 4096; i += 256) my |= (mw[i] > 1u) ? 1 : 0;
  if (my) atomicOr(&bad, 1);
  int g = 0;
  for (int i = t; i < 4096; i += 256) {
    unsigned lo = nodew[i] & 0xFFFFu;
    unsigned e = (lo >> 7) & 0xFFu;
    g += (lo == 0u || (e >= 100u && e <= 141u)) ? 1 : 0;
  }
  atomicAdd(&good, g);
  int ok = 1;
  if (t < 64) {  // wave 0: MFMA A/B/D layout self-test with asymmetric exact-int operands
    const int m = t & 15, quad = t >> 4;
    bf16x8 aF, bF;
#pragma unroll
    for (int j = 0; j < 8; ++j) {
      const int k = quad * 8 + j;
      aF[j] = (__bf16)(float)(((m * 7 + k * 3) % 5) - 2);
      bF[j] = (__bf16)(float)(((k * 5 + m * 11) % 7) - 3);
    }
    f32x4 d; d[0] = 0.f; d[1] = 0.f; d[2] = 0.f; d[3] = 0.f;
    d = __builtin_amdgcn_mfma_f32_16x16x32_bf16(aF, bF, d, 0, 0, 0);
#pragma unroll
    for (int r = 0; r < 4; ++r) {
      const int row = quad * 4 + r, col = m;
      float ex = 0.f;
      for (int k = 0; k < 32; ++k)
        ex += (float)(((row * 7 + k * 3) % 5) - 2) * (float)(((k * 5 + col * 11) % 7) - 3);
      if (d[r] != ex) ok = 0;
    }
    ok = __all(ok);
  }
  __syncthreads();
  if (t == 0) {
    flags[0] = bad;
    flags[1] = (good > 2048) ? 1 : 0;
    flags[2] = ok;
  }
}

// ---------- h_num (tiny MLP) + zero the mean accumulators ----------
__global__ __launch_bounds__(256) void k_head(
    const void* __restrict__ numerical, const void* __restrict__ W1,
    const void* __restrict__ b1, const void* __restrict__ W2,
    const void* __restrict__ b2, const int* __restrict__ flags,
    float* __restrict__ hnum, float* __restrict__ sums, float* __restrict__ counts) {
  __shared__ float numf[2][32];
  __shared__ float u[2][128];
  const int t = threadIdx.x;
  const int dt = flags[1];
  if (t < 64) numf[t >> 5][t & 31] = ldf(numerical, t, dt);
  if (t < 128) sums[t] = 0.f;
  if (t < 2) counts[t] = 0.f;
  __syncthreads();
  {
    const int b = t >> 7, j = t & 127;
    float acc = ldf(b1, j, dt);
#pragma unroll
    for (int k = 0; k < 32; ++k) acc += numf[b][k] * ldf(W1, k * 128 + j, dt);
    u[b][j] = tanh_f(acc);
  }
  __syncthreads();
  if (t < 128) {
    const int b = t >> 6, d = t & 63;
    float acc = ldf(b2, d, dt);
#pragma unroll
    for (int k = 0; k < 128; ++k) acc += u[b][k] * ldf(W2, k * 64 + d, dt);
    hnum[b * 64 + d] = tanh_f(acc);
  }
}

// ---------- MFMA path: h = tanh(node@Wn+bn); AB = h @ [Wa|Wb] ----------
__global__ __launch_bounds__(256) void k_nodes(
    const void* __restrict__ node, const void* __restrict__ Wn,
    const void* __restrict__ bn, const void* __restrict__ We,
    const int* __restrict__ flags, __bf16* __restrict__ AB) {
  if (!flags[2]) return;  // MFMA layout self-test failed -> VALU fallback runs
  const int dt = flags[1];
  const int t = threadIdx.x;
  const int wave = t >> 6, lane = t & 63;
  const int m = lane & 15, quad = lane >> 4;

  bf16x8 wnF[4];
#pragma unroll
  for (int nt = 0; nt < 4; ++nt) {
    const int c = m + 16 * nt;
#pragma unroll
    for (int j = 0; j < 8; ++j) wnF[nt][j] = (__bf16)ldf(Wn, (quad * 8 + j) * 64 + c, dt);
  }
  bf16x8 weF[8][2];
#pragma unroll
  for (int nt = 0; nt < 8; ++nt) {
    const int c2 = m + 16 * nt;
#pragma unroll
    for (int kh = 0; kh < 2; ++kh) {
#pragma unroll
      for (int j = 0; j < 8; ++j) {
        const int k = kh * 32 + quad * 8 + j;
        weF[nt][kh][j] = (__bf16)((c2 < 64) ? ldf(We, k * 64 + c2, dt)
                                            : ldf(We, (k + 64) * 64 + (c2 - 64), dt));
      }
    }
  }
  float bnv[4];
#pragma unroll
  for (int nt = 0; nt < 4; ++nt) bnv[nt] = ldf(bn, m + 16 * nt, dt);

  const long r0 = ((long)blockIdx.x * 4 + wave) * 16;
  bf16x8 aF;
  if (dt) {
    aF = *(const bf16x8*)((const __bf16*)node + (r0 + m) * 32 + quad * 8);
  } else {
    const float* p = (const float*)node + (r0 + m) * 32 + quad * 8;
    f32x4 v0 = *(const f32x4*)p, v1 = *(const f32x4*)(p + 4);
#pragma unroll
    for (int j = 0; j < 4; ++j) { aF[j] = (__bf16)v0[j]; aF[4 + j] = (__bf16)v1[j]; }
  }

  f32x4 accA[4];
#pragma unroll
  for (int nt = 0; nt < 4; ++nt) {
    f32x4 c; c[0] = bnv[nt]; c[1] = bnv[nt]; c[2] = bnv[nt]; c[3] = bnv[nt];
    accA[nt] = c;
  }
#pragma unroll
  for (int nt = 0; nt < 4; ++nt)
    accA[nt] = __builtin_amdgcn_mfma_f32_16x16x32_bf16(aF, wnF[nt], accA[nt], 0, 0, 0);

  __shared__ __bf16 hl[4][16][64];
#pragma unroll
  for (int nt = 0; nt < 4; ++nt)
#pragma unroll
    for (int r = 0; r < 4; ++r)
      hl[wave][quad * 4 + r][m + 16 * nt] = (__bf16)tanh_f(accA[nt][r]);
  __syncthreads();

  bf16x8 hF[2];
#pragma unroll
  for (int kh = 0; kh < 2; ++kh)
    hF[kh] = *(const bf16x8*)&hl[wave][m][kh * 32 + quad * 8];

  f32x4 accB[8];
#pragma unroll
  for (int nt = 0; nt < 8; ++nt) {
    f32x4 z; z[0] = 0.f; z[1] = 0.f; z[2] = 0.f; z[3] = 0.f;
    accB[nt] = z;
  }
#pragma unroll
  for (int nt = 0; nt < 8; ++nt) {
    accB[nt] = __builtin_amdgcn_mfma_f32_16x16x32_bf16(hF[0], weF[nt][0], accB[nt], 0, 0, 0);
    accB[nt] = __builtin_amdgcn_mfma_f32_16x16x32_bf16(hF[1], weF[nt][1], accB[nt], 0, 0, 0);
  }
#pragma unroll
  for (int nt = 0; nt < 8; ++nt)
#pragma unroll
    for (int r = 0; r < 4; ++r)
      AB[(r0 + quad * 4 + r) * 128 + m + 16 * nt] = (__bf16)accB[nt][r];
}

// ---------- VALU fallback (runs only if MFMA self-test failed) ----------
__global__ __launch_bounds__(256) void k_h_valu(
    const void* __restrict__ node, const void* __restrict__ Wn,
    const void* __restrict__ bn, const int* __restrict__ flags,
    __bf16* __restrict__ hbuf) {
  if (flags[2]) return;
  const int dt = flags[1];
  const int t = threadIdx.x;
  __shared__ float WnL[32 * 64];
  __shared__ float bnL[64];
  for (int i = t; i < 2048; i += 256) WnL[i] = ldf(Wn, i, dt);
  if (t < 64) bnL[t] = ldf(bn, t, dt);
  __syncthreads();
  const long r = (long)blockIdx.x * 64 + (t >> 2);
  const int c0 = (t & 3) * 16;
  float nv[32];
#pragma unroll
  for (int k = 0; k < 32; ++k) nv[k] = ldf(node, r * 32 + k, dt);
  float acc[16];
#pragma unroll
  for (int c = 0; c < 16; ++c) acc[c] = bnL[c0 + c];
#pragma unroll
  for (int k = 0; k < 32; ++k)
#pragma unroll
    for (int c = 0; c < 16; ++c) acc[c] += nv[k] * WnL[k * 64 + c0 + c];
#pragma unroll
  for (int c = 0; c < 16; ++c) hbuf[r * 64 + c0 + c] = (__bf16)tanh_f(acc[c]);
}

__global__ __launch_bounds__(256) void k_ab_valu(
    const __bf16* __restrict__ hbuf, const void* __restrict__ We,
    const int* __restrict__ flags, __bf16* __restrict__ AB) {
  if (flags[2]) return;
  const int dt = flags[1];
  const int t = threadIdx.x;
  __shared__ __bf16 WeL[64 * 128];
  for (int i = t; i < 8192; i += 256) {
    const int k = i >> 7, c2 = i & 127;
    WeL[i] = (__bf16)((c2 < 64) ? ldf(We, k * 64 + c2, dt)
                                : ldf(We, (k + 64) * 64 + (c2 - 64), dt));
  }
  __syncthreads();
  const long r = (long)blockIdx.x * 32 + (t >> 3);
  const int c0 = (t & 7) * 16;
  float hv[64];
#pragma unroll
  for (int k = 0; k < 64; ++k) hv[k] = (float)hbuf[r * 64 + k];
  float acc[16];
#pragma unroll
  for (int c = 0; c < 16; ++c) acc[c] = 0.f;
#pragma unroll
  for (int k = 0; k < 64; ++k)
#pragma unroll
    for (int c = 0; c < 16; ++c) acc[c] += hv[k] * (float)WeL[k * 128 + c0 + c];
#pragma unroll
  for (int c = 0; c < 16; ++c) AB[r * 128 + c0 + c] = (__bf16)acc[c];
}

// ---------- per-edge: gather, tanh both ways, mask, write fp32 + reduce ----------
__global__ __launch_bounds__(256) void k_edges(
    const int2* __restrict__ eidx, const void* __restrict__ emask,
    const int* __restrict__ flags, const __bf16* __restrict__ AB,
    const void* __restrict__ be, float* __restrict__ sums,
    float* __restrict__ counts, float* __restrict__ outp) {
  const int nbPerB = (NE + 255) / 256;
  const int b = blockIdx.x / nbPerB;
  const long e0 = (long)(blockIdx.x % nbPerB) * 256;
  const int t = threadIdx.x;
  const int L = t & 3, eo = t >> 2;
  __shared__ float beL[64];
  __shared__ float red[256 * 17];
  __shared__ float cnt[64];
  const int dt = flags[1];
  if (t < 64) beL[t] = ldf(be, t, dt);
  __syncthreads();
  const int mode = flags[0];
  const __bf16* ABb = AB + (long)b * NN * 128;
  const int d0 = L * 16;
  float psum[16];
#pragma unroll
  for (int k = 0; k < 16; ++k) psum[k] = 0.f;
  float pcnt = 0.f;

  for (int pass = 0; pass < 4; ++pass) {
    const long e = e0 + pass * 64 + eo;
    if (e < NE) {
      const int2 ij = eidx[(long)b * NE + e];
      float mval;
      if (mode) mval = (float)(((const unsigned char*)emask)[(long)b * NE + e]);
      else      mval = (float)(((const int*)emask)[(long)b * NE + e]);
      const __bf16* Ri = ABb + (long)ij.x * 128;
      const __bf16* Rj = ABb + (long)ij.y * 128;
      bf16x8 ai0 = *(const bf16x8*)(Ri + d0);
      bf16x8 ai1 = *(const bf16x8*)(Ri + d0 + 8);
      bf16x8 bi0 = *(const bf16x8*)(Ri + 64 + d0);
      bf16x8 bi1 = *(const bf16x8*)(Ri + 64 + d0 + 8);
      bf16x8 aj0 = *(const bf16x8*)(Rj + d0);
      bf16x8 aj1 = *(const bf16x8*)(Rj + d0 + 8);
      bf16x8 bj0 = *(const bf16x8*)(Rj + 64 + d0);
      bf16x8 bj1 = *(const bf16x8*)(Rj + 64 + d0 + 8);
      float ov[16];
#pragma unroll
      for (int k = 0; k < 8; ++k) {
        const float bias = beL[d0 + k];
        const float s12 = (float)ai0[k] + (float)bj0[k] + bias;
        const float s21 = (float)aj0[k] + (float)bi0[k] + bias;
        const float v = 0.5f * (tanh_f(s12) + tanh_f(s21)) * mval;
        psum[k] += v;
        ov[k] = v;
      }
#pragma unroll
      for (int k = 0; k < 8; ++k) {
        const float bias = beL[d0 + 8 + k];
        const float s12 = (float)ai1[k] + (float)bj1[k] + bias;
        const float s21 = (float)aj1[k] + (float)bi1[k] + bias;
        const float v = 0.5f * (tanh_f(s12) + tanh_f(s21)) * mval;
        psum[8 + k] += v;
        ov[8 + k] = v;
      }
      float* op = outp + ((long)b * NE + e) * 64 + d0;
#pragma unroll
      for (int u = 0; u < 4; ++u) {
        f32x4 w; w[0] = ov[4 * u]; w[1] = ov[4 * u + 1]; w[2] = ov[4 * u + 2]; w[3] = ov[4 * u + 3];
        *(f32x4*)(op + 4 * u) = w;
      }
      if (L == 0) pcnt += mval;
    }
  }

#pragma unroll
  for (int k = 0; k < 16; ++k) red[t * 17 + k] = psum[k];
  if (L == 0) cnt[eo] = pcnt;
  __syncthreads();
  if (t < 64) {
    const int L2 = t >> 4, k2 = t & 15;
    float s = 0.f;
    for (int mm = 0; mm < 64; ++mm) s += red[(L2 + 4 * mm) * 17 + k2];
    atomicAdd(&sums[b * 64 + t], s);
  }
  if (t == 0) {
    float c = 0.f;
    for (int i = 0; i < 64; ++i) c += cnt[i];
    atomicAdd(&counts[b], c);
  }
}

// ---------- finalize state_value = [h_num | mean | stage] (fp32 out) ----------
__global__ __launch_bounds__(512) void k_final(
    const float* __restrict__ hnum, const float* __restrict__ sums,
    const float* __restrict__ counts, const void* __restrict__ stage,
    const int* __restrict__ flags, float* __restrict__ out) {
  const int t = threadIdx.x;
  const int dt = flags[1];
  if (t < 260) {
    const int b = t / 130, c = t % 130;
    float v;
    if (c < 64) v = hnum[b * 64 + c];
    else if (c < 128) v = sums[b * 64 + (c - 64)] / counts[b];
    else v = ldf(stage, b * 2 + (c - 128), dt);
    out[(long)NB * NE * 64 + (long)b * 130 + c] = v;
  }
}

extern "C" void kernel_launch(void* const* d_in, const int* in_sizes, int n_in,
                              void* d_out, int out_size, void* d_ws, size_t ws_size,
                              hipStream_t stream) {
  const void* numerical = d_in[0];
  const void* node      = d_in[1];
  const int2* eidx      = (const int2*)d_in[2];
  const void* emask     = d_in[3];
  const void* stage     = d_in[4];
  const void* W1 = d_in[5];
  const void* b1 = d_in[6];
  const void* W2 = d_in[7];
  const void* b2 = d_in[8];
  const void* Wn = d_in[9];
  const void* bn = d_in[10];
  const void* We = d_in[11];
  const void* be = d_in[12];

  char* ws = (char*)d_ws;
  int*    flags  = (int*)ws;
  float*  sums   = (float*)(ws + 256);
  float*  counts = (float*)(ws + 1024);
  float*  hnum   = (float*)(ws + 1280);
  __bf16* AB     = (__bf16*)(ws + 4096);                       // 200000*128*2B = 51.2 MB
  __bf16* hbuf   = (__bf16*)(ws + 4096 + (size_t)NB * NN * 128 * 2);  // 25.6 MB (fallback only)
  float*  outp   = (float*)d_out;

  k_detect<<<1, 256, 0, stream>>>((const unsigned int*)emask, (const unsigned int*)node, flags);
  k_head<<<1, 256, 0, stream>>>(numerical, W1, b1, W2, b2, flags, hnum, sums, counts);
  k_nodes<<<(NB * NN) / 64, 256, 0, stream>>>(node, Wn, bn, We, flags, AB);
  k_h_valu<<<(NB * NN) / 64, 256, 0, stream>>>(node, Wn, bn, flags, hbuf);
  k_ab_valu<<<(NB * NN) / 32, 256, 0, stream>>>(hbuf, We, flags, AB);
  k_edges<<<NB * ((NE + 255) / 256), 256, 0, stream>>>(eidx, emask, flags, AB, be, sums, counts, outp);
  k_final<<<1, 512, 0, stream>>>(hnum, sums, counts, stage, flags, outp);
}

// Round 3
// 473.419 us; speedup vs baseline: 1.0813x; 1.0813x over previous
//
#include <hip/hip_runtime.h>
#include <hip/hip_bf16.h>

typedef __attribute__((ext_vector_type(4))) float  f32x4;
typedef __attribute__((ext_vector_type(8))) __bf16 bf16x8;

#define NB 2
#define NN 100000
#define NE 400000

__device__ __forceinline__ float tanh_f(float x) {
  float xc = fminf(fmaxf(x, -10.f), 10.f);
  float e = __expf(2.f * xc);
  return 1.f - 2.f / (e + 1.f);
}

// dtype-branched float load: bf=1 -> buffer is bf16, bf=0 -> fp32
__device__ __forceinline__ float ldf(const void* p, long i, int bf) {
  return bf ? (float)((const __bf16*)p)[i] : ((const float*)p)[i];
}

// ---------- one-block setup: dtype detect + h_num MLP + weight-fragment pack ----------
// flags[0]=mask-is-bytes, flags[1]=inputs-are-bf16
__global__ __launch_bounds__(256) void k_setup(
    const unsigned int* __restrict__ mw, const unsigned int* __restrict__ nodew,
    const void* __restrict__ numerical, const void* __restrict__ W1,
    const void* __restrict__ b1, const void* __restrict__ W2,
    const void* __restrict__ b2, const void* __restrict__ Wn,
    const void* __restrict__ bn, const void* __restrict__ We,
    int* __restrict__ flags, float* __restrict__ hnum,
    float* __restrict__ sums, float* __restrict__ counts,
    __bf16* __restrict__ packWn, __bf16* __restrict__ packWe,
    float* __restrict__ packBn) {
  __shared__ int badS, goodS, dtS;
  __shared__ float numf[2][32];
  __shared__ float u[2][128];
  const int t = threadIdx.x;
  if (t == 0) { badS = 0; goodS = 0; }
  __syncthreads();
  int my = 0;
  for (int i = t; i < 4096; i += 256) my |= (mw[i] > 1u) ? 1 : 0;
  if (my) atomicOr(&badS, 1);
  int g = 0;
  for (int i = t; i < 4096; i += 256) {
    unsigned lo = nodew[i] & 0xFFFFu;
    unsigned e = (lo >> 7) & 0xFFu;
    g += (lo == 0u || (e >= 100u && e <= 141u)) ? 1 : 0;
  }
  atomicAdd(&goodS, g);
  __syncthreads();
  if (t == 0) {
    flags[0] = badS;
    dtS = (goodS > 2048) ? 1 : 0;
    flags[1] = dtS;
  }
  __syncthreads();
  const int dt = dtS;

  if (t < 128) sums[t] = 0.f;
  if (t < 2) counts[t] = 0.f;
  if (t < 64) numf[t >> 5][t & 31] = ldf(numerical, t, dt);
  __syncthreads();
  {
    const int b = t >> 7, j = t & 127;
    float acc = ldf(b1, j, dt);
#pragma unroll
    for (int k = 0; k < 32; ++k) acc += numf[b][k] * ldf(W1, k * 128 + j, dt);
    u[b][j] = tanh_f(acc);
  }
  __syncthreads();
  if (t < 128) {
    const int b = t >> 6, d = t & 63;
    float acc = ldf(b2, d, dt);
#pragma unroll
    for (int k = 0; k < 128; ++k) acc += u[b][k] * ldf(W2, k * 64 + d, dt);
    hnum[b * 64 + d] = tanh_f(acc);
  }

  // pack per-lane MFMA B-fragments (layout B[k=quad*8+j][n], n = m+16*nt)
  if (t < 64) {
    const int m = t & 15, quad = t >> 4;
#pragma unroll
    for (int nt = 0; nt < 4; ++nt) {
      const int c = m + 16 * nt;
#pragma unroll
      for (int j = 0; j < 8; ++j)
        packWn[t * 32 + nt * 8 + j] = (__bf16)ldf(Wn, (quad * 8 + j) * 64 + c, dt);
      packBn[t * 4 + nt] = ldf(bn, c, dt);
    }
    // concat weight C(64x128): C[k][c2] = c2<64 ? We[k][c2] : We[k+64][c2-64]
#pragma unroll
    for (int f = 0; f < 16; ++f) {
      const int nt = f >> 1, kh = f & 1;
      const int c2 = m + 16 * nt;
#pragma unroll
      for (int j = 0; j < 8; ++j) {
        const int k = kh * 32 + quad * 8 + j;
        packWe[t * 128 + f * 8 + j] =
            (__bf16)((c2 < 64) ? ldf(We, k * 64 + c2, dt)
                               : ldf(We, (k + 64) * 64 + (c2 - 64), dt));
      }
    }
  }
}

// ---------- per-node MFMA: h = tanh(node@Wn+bn); AB = h @ [Wa|Wb] ----------
// block = 256 (4 waves); each wave 16 rows; grid = 200000/64 = 3125.
__global__ __launch_bounds__(256) void k_nodes(
    const void* __restrict__ node, const __bf16* __restrict__ packWn,
    const __bf16* __restrict__ packWe, const float* __restrict__ packBn,
    const int* __restrict__ flags, __bf16* __restrict__ AB) {
  const int t = threadIdx.x;
  const int wave = t >> 6, lane = t & 63;
  const int m = lane & 15, quad = lane >> 4;
  const int dt = flags[1];

  bf16x8 wnF[4];
#pragma unroll
  for (int nt = 0; nt < 4; ++nt)
    wnF[nt] = *(const bf16x8*)(packWn + lane * 32 + nt * 8);
  bf16x8 weF[16];
#pragma unroll
  for (int f = 0; f < 16; ++f)
    weF[f] = *(const bf16x8*)(packWe + lane * 128 + f * 8);
  float bnv[4];
#pragma unroll
  for (int nt = 0; nt < 4; ++nt) bnv[nt] = packBn[lane * 4 + nt];

  const long r0 = ((long)blockIdx.x * 4 + wave) * 16;
  // A-frag: A[m=lane&15][k=quad*8+j], 16 contiguous bytes in bf16 mode
  bf16x8 aF;
  if (dt) {
    aF = *(const bf16x8*)((const __bf16*)node + (r0 + m) * 32 + quad * 8);
  } else {
    const float* p = (const float*)node + (r0 + m) * 32 + quad * 8;
    f32x4 v0 = *(const f32x4*)p, v1 = *(const f32x4*)(p + 4);
#pragma unroll
    for (int j = 0; j < 4; ++j) { aF[j] = (__bf16)v0[j]; aF[4 + j] = (__bf16)v1[j]; }
  }

  f32x4 accA[4];
#pragma unroll
  for (int nt = 0; nt < 4; ++nt) {
    f32x4 c; c[0] = bnv[nt]; c[1] = bnv[nt]; c[2] = bnv[nt]; c[3] = bnv[nt];
    accA[nt] = c;
  }
#pragma unroll
  for (int nt = 0; nt < 4; ++nt)
    accA[nt] = __builtin_amdgcn_mfma_f32_16x16x32_bf16(aF, wnF[nt], accA[nt], 0, 0, 0);

  // C-layout -> A-layout transpose via LDS (tanh applied here)
  __shared__ __bf16 hl[4][16][64];
#pragma unroll
  for (int nt = 0; nt < 4; ++nt)
#pragma unroll
    for (int r = 0; r < 4; ++r)
      hl[wave][quad * 4 + r][m + 16 * nt] = (__bf16)tanh_f(accA[nt][r]);
  __syncthreads();

  bf16x8 hF[2];
#pragma unroll
  for (int kh = 0; kh < 2; ++kh)
    hF[kh] = *(const bf16x8*)&hl[wave][m][kh * 32 + quad * 8];

  f32x4 accB[8];
#pragma unroll
  for (int nt = 0; nt < 8; ++nt) {
    f32x4 z; z[0] = 0.f; z[1] = 0.f; z[2] = 0.f; z[3] = 0.f;
    accB[nt] = z;
  }
#pragma unroll
  for (int nt = 0; nt < 8; ++nt) {
    accB[nt] = __builtin_amdgcn_mfma_f32_16x16x32_bf16(hF[0], weF[2 * nt], accB[nt], 0, 0, 0);
    accB[nt] = __builtin_amdgcn_mfma_f32_16x16x32_bf16(hF[1], weF[2 * nt + 1], accB[nt], 0, 0, 0);
  }

  // C-layout -> row-major via LDS, then 4x16B vector stores per lane
  __shared__ __bf16 ob[4][16][136];  // +8 pad: 16B-aligned rows, <=4-way banks
#pragma unroll
  for (int nt = 0; nt < 8; ++nt)
#pragma unroll
    for (int r = 0; r < 4; ++r)
      ob[wave][quad * 4 + r][m + 16 * nt] = (__bf16)accB[nt][r];
  __syncthreads();
  {
    const int row = lane >> 2, c0 = (lane & 3) * 32;
    const long gr = r0 + row;
#pragma unroll
    for (int u = 0; u < 4; ++u) {
      bf16x8 v = *(const bf16x8*)&ob[wave][row][c0 + u * 8];
      *(bf16x8*)(AB + gr * 128 + c0 + u * 8) = v;
    }
  }
}

// ---------- per-edge: gather, tanh both ways, mask, NT-write fp32 + reduce ----------
__global__ __launch_bounds__(256) void k_edges(
    const int2* __restrict__ eidx, const void* __restrict__ emask,
    const int* __restrict__ flags, const __bf16* __restrict__ AB,
    const void* __restrict__ be, float* __restrict__ sums,
    float* __restrict__ counts, float* __restrict__ outp) {
  const int nbPerB = (NE + 255) / 256;
  const int b = blockIdx.x / nbPerB;
  const long e0 = (long)(blockIdx.x % nbPerB) * 256;
  const int t = threadIdx.x;
  const int L = t & 3, eo = t >> 2;
  __shared__ float beL[64];
  __shared__ float red[256 * 17];
  __shared__ float cnt[64];
  const int dt = flags[1];
  const int mode = flags[0];
  if (t < 64) beL[t] = ldf(be, t, dt);
  __syncthreads();
  const __bf16* ABb = AB + (long)b * NN * 128;
  const int d0 = L * 16;
  float psum[16];
#pragma unroll
  for (int k = 0; k < 16; ++k) psum[k] = 0.f;
  float pcnt = 0.f;

#pragma unroll
  for (int pass = 0; pass < 4; ++pass) {
    const long e = e0 + pass * 64 + eo;
    const int valid = (e < NE) ? 1 : 0;
    const long ec = valid ? e : (NE - 1);
    const int2 ij = eidx[(long)b * NE + ec];
    float mval;
    if (mode) mval = (float)(((const unsigned char*)emask)[(long)b * NE + ec]);
    else      mval = (float)(((const int*)emask)[(long)b * NE + ec]);
    if (!valid) mval = 0.f;
    const __bf16* Ri = ABb + (long)ij.x * 128;
    const __bf16* Rj = ABb + (long)ij.y * 128;
    bf16x8 ai0 = *(const bf16x8*)(Ri + d0);
    bf16x8 ai1 = *(const bf16x8*)(Ri + d0 + 8);
    bf16x8 bi0 = *(const bf16x8*)(Ri + 64 + d0);
    bf16x8 bi1 = *(const bf16x8*)(Ri + 64 + d0 + 8);
    bf16x8 aj0 = *(const bf16x8*)(Rj + d0);
    bf16x8 aj1 = *(const bf16x8*)(Rj + d0 + 8);
    bf16x8 bj0 = *(const bf16x8*)(Rj + 64 + d0);
    bf16x8 bj1 = *(const bf16x8*)(Rj + 64 + d0 + 8);
    float ov[16];
#pragma unroll
    for (int k = 0; k < 8; ++k) {
      const float bias = beL[d0 + k];
      const float s12 = (float)ai0[k] + (float)bj0[k] + bias;
      const float s21 = (float)aj0[k] + (float)bi0[k] + bias;
      const float v = 0.5f * (tanh_f(s12) + tanh_f(s21)) * mval;
      psum[k] += v;
      ov[k] = v;
    }
#pragma unroll
    for (int k = 0; k < 8; ++k) {
      const float bias = beL[d0 + 8 + k];
      const float s12 = (float)ai1[k] + (float)bj1[k] + bias;
      const float s21 = (float)aj1[k] + (float)bi1[k] + bias;
      const float v = 0.5f * (tanh_f(s12) + tanh_f(s21)) * mval;
      psum[8 + k] += v;
      ov[8 + k] = v;
    }
    if (valid) {
      float* op = outp + ((long)b * NE + e) * 64 + d0;
#pragma unroll
      for (int u = 0; u < 4; ++u) {
        f32x4 w; w[0] = ov[4 * u]; w[1] = ov[4 * u + 1];
        w[2] = ov[4 * u + 2]; w[3] = ov[4 * u + 3];
        __builtin_nontemporal_store(w, (f32x4*)(op + 4 * u));
      }
    }
    if (L == 0) pcnt += mval;
  }

#pragma unroll
  for (int k = 0; k < 16; ++k) red[t * 17 + k] = psum[k];
  if (L == 0) cnt[eo] = pcnt;
  __syncthreads();
  if (t < 64) {
    const int L2 = t >> 4, k2 = t & 15;
    float s = 0.f;
    for (int mm = 0; mm < 64; ++mm) s += red[(L2 + 4 * mm) * 17 + k2];
    atomicAdd(&sums[b * 64 + t], s);
  }
  if (t == 0) {
    float c = 0.f;
    for (int i = 0; i < 64; ++i) c += cnt[i];
    atomicAdd(&counts[b], c);
  }
}

// ---------- finalize state_value = [h_num | mean | stage] (fp32 out) ----------
__global__ __launch_bounds__(512) void k_final(
    const float* __restrict__ hnum, const float* __restrict__ sums,
    const float* __restrict__ counts, const void* __restrict__ stage,
    const int* __restrict__ flags, float* __restrict__ out) {
  const int t = threadIdx.x;
  const int dt = flags[1];
  if (t < 260) {
    const int b = t / 130, c = t % 130;
    float v;
    if (c < 64) v = hnum[b * 64 + c];
    else if (c < 128) v = sums[b * 64 + (c - 64)] / counts[b];
    else v = ldf(stage, b * 2 + (c - 128), dt);
    out[(long)NB * NE * 64 + (long)b * 130 + c] = v;
  }
}

extern "C" void kernel_launch(void* const* d_in, const int* in_sizes, int n_in,
                              void* d_out, int out_size, void* d_ws, size_t ws_size,
                              hipStream_t stream) {
  const void* numerical = d_in[0];
  const void* node      = d_in[1];
  const int2* eidx      = (const int2*)d_in[2];
  const void* emask     = d_in[3];
  const void* stage     = d_in[4];
  const void* W1 = d_in[5];
  const void* b1 = d_in[6];
  const void* W2 = d_in[7];
  const void* b2 = d_in[8];
  const void* Wn = d_in[9];
  const void* bn = d_in[10];
  const void* We = d_in[11];
  const void* be = d_in[12];

  char* ws = (char*)d_ws;
  int*    flags  = (int*)ws;
  float*  sums   = (float*)(ws + 256);    // [2][64]
  float*  counts = (float*)(ws + 1024);   // [2]
  float*  hnum   = (float*)(ws + 1280);   // [2][64]
  float*  packBn = (float*)(ws + 2048);   // 64*4*4B = 1 KB
  __bf16* packWn = (__bf16*)(ws + 4096);  // 64*32*2B = 4 KB
  __bf16* packWe = (__bf16*)(ws + 8192);  // 64*128*2B = 16 KB
  __bf16* AB     = (__bf16*)(ws + 32768); // 200000*128*2B = 51.2 MB
  float*  outp   = (float*)d_out;

  k_setup<<<1, 256, 0, stream>>>((const unsigned int*)emask, (const unsigned int*)node,
                                 numerical, W1, b1, W2, b2, Wn, bn, We,
                                 flags, hnum, sums, counts, packWn, packWe, packBn);
  k_nodes<<<(NB * NN) / 64, 256, 0, stream>>>(node, packWn, packWe, packBn, flags, AB);
  k_edges<<<NB * ((NE + 255) / 256), 256, 0, stream>>>(eidx, emask, flags, AB, be, sums, counts, outp);
  k_final<<<1, 512, 0, stream>>>(hnum, sums, counts, stage, flags, outp);
}